// Round 16
// baseline (41.879 us; speedup 1.0000x reference)
//
#include <hip/hip_runtime.h>
#include <cstdint>

namespace {

constexpr int NB = 320;   // batch
constexpr int ND = 128;   // feature dim
constexpr int NC = 80;    // label dim
constexpr int NANCH = 30;
constexpr int NW = 5;     // 64-bit words per 320-bit row

// ---- workspace layout (byte offsets) ----
constexpr size_t OFF_DIV  = 0;        // float[320]
constexpr size_t OFF_ASUM = 1280;     // double[320]
constexpr size_t OFF_ACNT = 3840;     // int[320]
constexpr size_t OFF_PACK = 5120;     // u64[640]
constexpr size_t OFF_TGTT = 10240;    // float4[32][320] = 163840 B

// K0: verbatim R15 (40 blocks x 8 rows).
__global__ __launch_bounds__(256) void k_prep(
    const float* __restrict__ tgt,
    const int* __restrict__ label,
    float4* __restrict__ tgtT4,
    unsigned long long* __restrict__ packed)
{
    const int tid = threadIdx.x;
    const int w = tid >> 6, lane = tid & 63;
    const int r0 = blockIdx.x * 8;

    __shared__ float4 tile4[8][33];

    {
        const int r = r0 + w;
        int l0 = label[r * NC + lane];
        int l1 = (lane < NC - 64) ? label[r * NC + 64 + lane] : 0;
        unsigned long long b0 = __ballot(l0 != 0);
        unsigned long long b1 = __ballot(l1 != 0);
        if (lane == 0) { packed[2 * r] = b0; packed[2 * r + 1] = b1; }

        const int r2 = r0 + 4 + w;
        l0 = label[r2 * NC + lane];
        l1 = (lane < NC - 64) ? label[r2 * NC + 64 + lane] : 0;
        b0 = __ballot(l0 != 0);
        b1 = __ballot(l1 != 0);
        if (lane == 0) { packed[2 * r2] = b0; packed[2 * r2 + 1] = b1; }
    }

    {
        const int r = tid >> 5, d4 = tid & 31;
        tile4[r][d4] = reinterpret_cast<const float4*>(tgt)[(r0 + r) * 32 + d4];
    }
    __syncthreads();
    {
        const int rr = tid & 7, d4 = tid >> 3;
        tgtT4[d4 * NB + r0 + rr] = tile4[rr][d4];
    }
}

// K1: verbatim R15 k_main.
__global__ __launch_bounds__(256) void k_main(
    const float* __restrict__ src,
    const float4* __restrict__ tgtT4,
    const unsigned long long* __restrict__ packed,
    float* __restrict__ divr,
    double* __restrict__ asum,
    int* __restrict__ acnt)
{
    const int a = blockIdx.x;
    const int tid = threadIdx.x;
    const int w = tid >> 6, lane = tid & 63;

    __shared__ float sa[ND];
    __shared__ float snsa;
    __shared__ float red[256];
    __shared__ unsigned long long pk[2 * NB];
    __shared__ float fdrow[NB];
    __shared__ unsigned long long pmask[NW], nmask[NW];
    __shared__ double wsum[4];

    if (tid < ND) sa[tid] = src[a * ND + tid];
    if (w == 0) {
        float s0 = src[a * ND + lane];
        float s1 = src[a * ND + lane + 64];
        float v = s0 * s0 + s1 * s1;
        for (int off = 32; off > 0; off >>= 1) v += __shfl_down(v, off);
        if (lane == 0) snsa = sqrtf(v);
    }
    for (int q = tid; q < 2 * NB; q += 256) pk[q] = packed[q];
    __syncthreads();

    const unsigned long long a0 = pk[2 * a], a1 = pk[2 * a + 1];
    const float nsa = snsa;

    float acc = 0.f;
#pragma unroll
    for (int it = 0; it < 2; ++it) {
        const int j = tid + 256 * it;
        if (j < NB) {
            float dot = 0.f, tn = 0.f;
#pragma unroll
            for (int d = 0; d < ND / 4; ++d) {
                float4 t = tgtT4[d * NB + j];
                dot += sa[4 * d + 0] * t.x + sa[4 * d + 1] * t.y +
                       sa[4 * d + 2] * t.z + sa[4 * d + 3] * t.w;
                tn += t.x * t.x + t.y * t.y + t.z * t.z + t.w * t.w;
            }
            float sim = dot / fmaxf(nsa * sqrtf(tn), 1e-8f);
            float f = fmaxf(1.0f - sim, 0.0f);
            fdrow[j] = f;
            acc += f;
        }
    }

    red[tid] = acc;
    __syncthreads();
    for (int st = 128; st > 0; st >>= 1) {
        if (tid < st) red[tid] += red[tid + st];
        __syncthreads();
    }
    if (tid == 0) divr[a] = red[0] / (float)NB;

    const float sna = sqrtf((float)(__popcll(a0) + __popcll(a1)));
#pragma unroll
    for (int it = 0; it < 2; ++it) {
        const int jj = tid + 256 * it;
        if (jj < NB) {
            const unsigned long long j0 = pk[2 * jj], j1 = pk[2 * jj + 1];
            const float snj = sqrtf((float)(__popcll(j0) + __popcll(j1)));
            const float denom = sna * snj;
            const float dotf = (float)(__popcll(a0 & j0) + __popcll(a1 & j1));
            const float ld = 1.0f - fminf(1.0f, dotf / denom);
            const bool valid = (jj != a) && (denom > 0.f);
            unsigned long long pb = __ballot(valid && (ld <= 0.2f));
            unsigned long long nb = __ballot(valid && (ld >= 0.5f));
            if (lane == 0) { pmask[jj >> 6] = pb; nmask[jj >> 6] = nb; }
        }
    }
    __syncthreads();

    double s = 0.0;
#pragma unroll
    for (int it = 0; it < 2; ++it) {
        const int jj = tid + 256 * it;
        if (jj < NB && ((nmask[jj >> 6] >> (jj & 63)) & 1ull)) {
            const float fn = fdrow[jj];
#pragma unroll
            for (int wd = 0; wd < NW; ++wd) {
                unsigned long long m = pmask[wd];
                while (m) {
                    const int b = __builtin_ctzll(m);
                    m &= m - 1;
                    float v = fdrow[wd * 64 + b] - fn + 0.5f;
                    if (v > 0.f) s += (double)v;
                }
            }
        }
    }
    for (int off = 32; off > 0; off >>= 1) s += __shfl_down(s, off);
    if (lane == 0) wsum[w] = s;
    __syncthreads();
    if (tid == 0) {
        int P = 0, N = 0;
#pragma unroll
        for (int wd = 0; wd < NW; ++wd) {
            P += __popcll(pmask[wd]);
            N += __popcll(nmask[wd]);
        }
        asum[a] = wsum[0] + wsum[1] + wsum[2] + wsum[3];
        acnt[a] = P * N;
    }
}

// K2: verbatim R15 k_final.
__global__ __launch_bounds__(320) void k_final(
    const float* __restrict__ divr,
    const double* __restrict__ asum,
    const int* __restrict__ acnt,
    float* __restrict__ out)
{
    const int tid = threadIdx.x;
    __shared__ float dv[NB];
    __shared__ int alist[NANCH];
    __shared__ double sl[NANCH];
    __shared__ int cl[NANCH];

    dv[tid] = divr[tid];
    __syncthreads();

    const float ve = dv[tid];
    int rank = 0;
#pragma unroll 8
    for (int j = 0; j < NB; ++j) {
        float vj = dv[j];
        rank += (vj > ve) || (vj == ve && j < tid);
    }
    if (rank < NANCH) alist[rank] = tid;
    __syncthreads();

    if (tid < NANCH) {
        sl[tid] = asum[alist[tid]];
        cl[tid] = acnt[alist[tid]];
    }
    __syncthreads();
    if (tid == 0) {
        double S = 0.0;
        long long C = 0;
        for (int r = 0; r < NANCH; ++r) { S += sl[r]; C += cl[r]; }
        out[0] = (float)(S / ((double)C + 1e-4));
    }
}

// no-op probe kernel: measures per-dispatch gap in the captured graph.
__global__ void k_nop() {}

} // namespace

extern "C" void kernel_launch(void* const* d_in, const int* in_sizes, int n_in,
                              void* d_out, int out_size, void* d_ws, size_t ws_size,
                              hipStream_t stream) {
    const int* label = (const int*)d_in[0];
    const float* src = (const float*)d_in[1];
    const float* tgt = (const float*)d_in[2];

    char* ws = (char*)d_ws;
    float* divr  = (float*)(ws + OFF_DIV);
    double* asum = (double*)(ws + OFF_ASUM);
    int* acnt    = (int*)(ws + OFF_ACNT);
    unsigned long long* packed = (unsigned long long*)(ws + OFF_PACK);
    float4* tgtT4 = (float4*)(ws + OFF_TGTT);

    k_prep <<<40, 256, 0, stream>>>(tgt, label, tgtT4, packed);
    k_main <<<NB, 256, 0, stream>>>(src, tgtT4, packed, divr, asum, acnt);
    k_final<<<1, 320, 0, stream>>>(divr, asum, acnt, (float*)d_out);

    // MEASUREMENT: 8 serialized no-op dispatches -> dur ≈ 29.7 + 8*g.
    for (int i = 0; i < 8; ++i) k_nop<<<1, 64, 0, stream>>>();
}

// Round 17
// 40.068 us; speedup vs baseline: 1.0452x; 1.0452x over previous
//
#include <hip/hip_runtime.h>
#include <cstdint>

namespace {

constexpr int NB = 320;   // batch
constexpr int ND = 128;   // feature dim
constexpr int NC = 80;    // label dim
constexpr int NANCH = 30;
constexpr int NW = 5;     // 64-bit words per 320-bit row

// ---- workspace layout (byte offsets) ----
constexpr size_t OFF_DIV  = 0;        // float[320]
constexpr size_t OFF_ASUM = 1280;     // double[320]
constexpr size_t OFF_ACNT = 3840;     // int[320]
constexpr size_t OFF_PACK = 5120;     // u64[640]
constexpr size_t OFF_TGTT = 10240;    // float4[32][320] = 163840 B
constexpr size_t OFF_CTR  = 174080;   // u32 arrival counter

// K0: verbatim R15 prep (40 blocks x 8 rows) + ctr zeroing.
__global__ __launch_bounds__(256) void k_prep(
    const float* __restrict__ tgt,
    const int* __restrict__ label,
    float4* __restrict__ tgtT4,
    unsigned long long* __restrict__ packed,
    unsigned int* __restrict__ ctr)
{
    const int tid = threadIdx.x;
    const int w = tid >> 6, lane = tid & 63;
    const int r0 = blockIdx.x * 8;

    __shared__ float4 tile4[8][33];

    if (blockIdx.x == 0 && tid == 0) *ctr = 0;   // stream-ordered before k_main

    {
        const int r = r0 + w;
        int l0 = label[r * NC + lane];
        int l1 = (lane < NC - 64) ? label[r * NC + 64 + lane] : 0;
        unsigned long long b0 = __ballot(l0 != 0);
        unsigned long long b1 = __ballot(l1 != 0);
        if (lane == 0) { packed[2 * r] = b0; packed[2 * r + 1] = b1; }

        const int r2 = r0 + 4 + w;
        l0 = label[r2 * NC + lane];
        l1 = (lane < NC - 64) ? label[r2 * NC + 64 + lane] : 0;
        b0 = __ballot(l0 != 0);
        b1 = __ballot(l1 != 0);
        if (lane == 0) { packed[2 * r2] = b0; packed[2 * r2 + 1] = b1; }
    }

    {
        const int r = tid >> 5, d4 = tid & 31;
        tile4[r][d4] = reinterpret_cast<const float4*>(tgt)[(r0 + r) * 32 + d4];
    }
    __syncthreads();
    {
        const int rr = tid & 7, d4 = tid >> 3;
        tgtT4[d4 * NB + r0 + rr] = tile4[rr][d4];
    }
}

// K1: R15 k_main phases byte-identical (256 threads), minus the pk LDS staging
// (each packed word is used once per block -> read global directly), plus the
// last-arriving-block tail that replaces k_final.
__global__ __launch_bounds__(256) void k_main(
    const float* __restrict__ src,
    const float4* __restrict__ tgtT4,
    const unsigned long long* __restrict__ packed,
    float* __restrict__ divr,
    double* __restrict__ asum,
    int* __restrict__ acnt,
    unsigned int* __restrict__ ctr,
    float* __restrict__ out)
{
    const int a = blockIdx.x;
    const int tid = threadIdx.x;
    const int w = tid >> 6, lane = tid & 63;

    __shared__ float sa[ND];
    __shared__ float snsa;
    __shared__ float red[256];
    __shared__ float fdrow[NB];
    __shared__ unsigned long long pmask[NW], nmask[NW];
    __shared__ double wsum[4];
    __shared__ int isLastS;
    __shared__ float dv[NB];
    __shared__ int alist[NANCH];
    __shared__ double sl[NANCH];
    __shared__ int cl[NANCH];

    if (tid < ND) sa[tid] = src[a * ND + tid];
    if (w == 0) {
        float s0 = src[a * ND + lane];
        float s1 = src[a * ND + lane + 64];
        float v = s0 * s0 + s1 * s1;
        for (int off = 32; off > 0; off >>= 1) v += __shfl_down(v, off);
        if (lane == 0) snsa = sqrtf(v);
    }
    __syncthreads();

    const float nsa = snsa;

    // ---- fd: identical to R15 ----
    float acc = 0.f;
#pragma unroll
    for (int it = 0; it < 2; ++it) {
        const int j = tid + 256 * it;
        if (j < NB) {
            float dot = 0.f, tn = 0.f;
#pragma unroll
            for (int d = 0; d < ND / 4; ++d) {
                float4 t = tgtT4[d * NB + j];
                dot += sa[4 * d + 0] * t.x + sa[4 * d + 1] * t.y +
                       sa[4 * d + 2] * t.z + sa[4 * d + 3] * t.w;
                tn += t.x * t.x + t.y * t.y + t.z * t.z + t.w * t.w;
            }
            float sim = dot / fmaxf(nsa * sqrtf(tn), 1e-8f);
            float f = fmaxf(1.0f - sim, 0.0f);
            fdrow[j] = f;
            acc += f;
        }
    }

    red[tid] = acc;
    __syncthreads();
    for (int st = 128; st > 0; st >>= 1) {
        if (tid < st) red[tid] += red[tid + st];
        __syncthreads();
    }
    if (tid == 0) divr[a] = red[0] / (float)NB;

    // ---- classification: direct global packed reads (values identical) ----
    const unsigned long long a0 = packed[2 * a], a1 = packed[2 * a + 1];
    const float sna = sqrtf((float)(__popcll(a0) + __popcll(a1)));
#pragma unroll
    for (int it = 0; it < 2; ++it) {
        const int jj = tid + 256 * it;
        if (jj < NB) {
            const unsigned long long j0 = packed[2 * jj], j1 = packed[2 * jj + 1];
            const float snj = sqrtf((float)(__popcll(j0) + __popcll(j1)));
            const float denom = sna * snj;
            const float dotf = (float)(__popcll(a0 & j0) + __popcll(a1 & j1));
            const float ld = 1.0f - fminf(1.0f, dotf / denom);
            const bool valid = (jj != a) && (denom > 0.f); // 0-label -> NaN in ref -> excluded
            unsigned long long pb = __ballot(valid && (ld <= 0.2f));
            unsigned long long nb = __ballot(valid && (ld >= 0.5f));
            if (lane == 0) { pmask[jj >> 6] = pb; nmask[jj >> 6] = nb; }
        }
    }
    __syncthreads();

    // ---- triplet sum: identical to R15 ----
    double s = 0.0;
#pragma unroll
    for (int it = 0; it < 2; ++it) {
        const int jj = tid + 256 * it;
        if (jj < NB && ((nmask[jj >> 6] >> (jj & 63)) & 1ull)) {
            const float fn = fdrow[jj];
#pragma unroll
            for (int wd = 0; wd < NW; ++wd) {
                unsigned long long m = pmask[wd];
                while (m) {
                    const int b = __builtin_ctzll(m);
                    m &= m - 1;
                    float v = fdrow[wd * 64 + b] - fn + 0.5f;
                    if (v > 0.f) s += (double)v;
                }
            }
        }
    }
    for (int off = 32; off > 0; off >>= 1) s += __shfl_down(s, off);
    if (lane == 0) wsum[w] = s;
    __syncthreads();
    if (tid == 0) {
        int P = 0, N = 0;
#pragma unroll
        for (int wd = 0; wd < NW; ++wd) {
            P += __popcll(pmask[wd]);
            N += __popcll(nmask[wd]);
        }
        asum[a] = wsum[0] + wsum[1] + wsum[2] + wsum[3];
        acnt[a] = P * N;
        __threadfence();                    // release divr/asum/acnt
        isLastS = (atomicAdd(ctr, 1u) == (unsigned)(NB - 1));
    }
    __syncthreads();
    if (!isLastS) return;
    __threadfence();                        // acquire all blocks' writes

    // ---- tail (last block only): rank top-30, gather, divide ----
    for (int q = tid; q < NB; q += 256) dv[q] = divr[q];
    __syncthreads();
#pragma unroll
    for (int it = 0; it < 2; ++it) {
        const int e = tid + 256 * it;       // it=1: wave 0 only (uniform)
        if (e < NB) {
            const float ve = dv[e];
            int rank = 0;
#pragma unroll 8
            for (int j = 0; j < NB; ++j) {
                float vj = dv[j];
                rank += (vj > ve) || (vj == ve && j < e);
            }
            if (rank < NANCH) alist[rank] = e;   // ranks unique; = lax.top_k
        }
    }
    __syncthreads();
    if (tid < NANCH) {
        sl[tid] = asum[alist[tid]];
        cl[tid] = acnt[alist[tid]];
    }
    __syncthreads();
    if (tid == 0) {
        double S = 0.0;
        long long C = 0;
        for (int r = 0; r < NANCH; ++r) { S += sl[r]; C += cl[r]; }
        out[0] = (float)(S / ((double)C + 1e-4));
    }
}

} // namespace

extern "C" void kernel_launch(void* const* d_in, const int* in_sizes, int n_in,
                              void* d_out, int out_size, void* d_ws, size_t ws_size,
                              hipStream_t stream) {
    const int* label = (const int*)d_in[0];
    const float* src = (const float*)d_in[1];
    const float* tgt = (const float*)d_in[2];

    char* ws = (char*)d_ws;
    float* divr  = (float*)(ws + OFF_DIV);
    double* asum = (double*)(ws + OFF_ASUM);
    int* acnt    = (int*)(ws + OFF_ACNT);
    unsigned long long* packed = (unsigned long long*)(ws + OFF_PACK);
    float4* tgtT4 = (float4*)(ws + OFF_TGTT);
    unsigned int* ctr = (unsigned int*)(ws + OFF_CTR);

    k_prep<<<40, 256, 0, stream>>>(tgt, label, tgtT4, packed, ctr);
    k_main<<<NB, 256, 0, stream>>>(src, tgtT4, packed, divr, asum, acnt, ctr,
                                   (float*)d_out);
}

// Round 18
// 26.138 us; speedup vs baseline: 1.6022x; 1.5330x over previous
//
#include <hip/hip_runtime.h>
#include <cstdint>

namespace {

constexpr int NB = 320;   // batch
constexpr int ND = 128;   // feature dim
constexpr int NC = 80;    // label dim
constexpr int NANCH = 30;
constexpr int NW = 5;     // 64-bit words per 320-bit row

// ---- workspace layout (byte offsets) ----
constexpr size_t OFF_DIV  = 0;        // float[320]
constexpr size_t OFF_ASUM = 1280;     // double[320]
constexpr size_t OFF_ACNT = 3840;     // int[320]
constexpr size_t OFF_PACK = 5120;     // u64[640]
constexpr size_t OFF_TGTT = 10240;    // float4[32][320] = 163840 B

// K0: verbatim R15 prep (40 blocks x 8 rows, coalesced both sides).
__global__ __launch_bounds__(256) void k_prep(
    const float* __restrict__ tgt,
    const int* __restrict__ label,
    float4* __restrict__ tgtT4,
    unsigned long long* __restrict__ packed)
{
    const int tid = threadIdx.x;
    const int w = tid >> 6, lane = tid & 63;
    const int r0 = blockIdx.x * 8;

    __shared__ float4 tile4[8][33];

    {
        const int r = r0 + w;
        int l0 = label[r * NC + lane];
        int l1 = (lane < NC - 64) ? label[r * NC + 64 + lane] : 0;
        unsigned long long b0 = __ballot(l0 != 0);
        unsigned long long b1 = __ballot(l1 != 0);
        if (lane == 0) { packed[2 * r] = b0; packed[2 * r + 1] = b1; }

        const int r2 = r0 + 4 + w;
        l0 = label[r2 * NC + lane];
        l1 = (lane < NC - 64) ? label[r2 * NC + 64 + lane] : 0;
        b0 = __ballot(l0 != 0);
        b1 = __ballot(l1 != 0);
        if (lane == 0) { packed[2 * r2] = b0; packed[2 * r2 + 1] = b1; }
    }

    {
        const int r = tid >> 5, d4 = tid & 31;
        tile4[r][d4] = reinterpret_cast<const float4*>(tgt)[(r0 + r) * 32 + d4];
    }
    __syncthreads();
    {
        const int rr = tid & 7, d4 = tid >> 3;
        tgtT4[d4 * NB + r0 + rr] = tile4[rr][d4];
    }
}

// K1: 320 threads (5 waves), 3 barriers. One column per thread everywhere.
// Per-element fd math textually identical to the absmax-0.0 lineage.
// divr/asum reduction orders changed (selection-safe / double-headroom-safe).
__global__ __launch_bounds__(320) void k_main(
    const float* __restrict__ src,
    const float4* __restrict__ tgtT4,
    const unsigned long long* __restrict__ packed,
    float* __restrict__ divr,
    double* __restrict__ asum,
    int* __restrict__ acnt)
{
    const int a = blockIdx.x;
    const int tid = threadIdx.x;          // 0..319
    const int w = tid >> 6, lane = tid & 63;

    __shared__ float sa[ND];
    __shared__ float snsa;
    __shared__ float fdrow[NB];
    __shared__ unsigned long long pmask[NW], nmask[NW];
    __shared__ float wred[NW];
    __shared__ double wsum[NW];

    if (tid < ND) sa[tid] = src[a * ND + tid];
    if (w == 0) {
        float s0 = src[a * ND + lane];
        float s1 = src[a * ND + lane + 64];
        float v = s0 * s0 + s1 * s1;
        for (int off = 32; off > 0; off >>= 1) v += __shfl_down(v, off);
        if (lane == 0) snsa = sqrtf(v);
    }
    __syncthreads();                                   // barrier 1

    const float nsa = snsa;

    // ---- fd: thread t -> column t (coalesced), identical expression tree ----
    {
        float dot = 0.f, tn = 0.f;
#pragma unroll
        for (int d = 0; d < ND / 4; ++d) {
            float4 t = tgtT4[d * NB + tid];
            dot += sa[4 * d + 0] * t.x + sa[4 * d + 1] * t.y +
                   sa[4 * d + 2] * t.z + sa[4 * d + 3] * t.w;
            tn += t.x * t.x + t.y * t.y + t.z * t.z + t.w * t.w;
        }
        float sim = dot / fmaxf(nsa * sqrtf(tn), 1e-8f);
        float f = fmaxf(1.0f - sim, 0.0f);
        fdrow[tid] = f;
        // diversity: per-wave shfl reduce (order changed; selection-safe)
        float af = f;
        for (int off = 32; off > 0; off >>= 1) af += __shfl_down(af, off);
        if (lane == 0) wred[w] = af;
    }

    // ---- classification: direct global packed reads; wave w -> word w ----
    const unsigned long long a0 = packed[2 * a], a1 = packed[2 * a + 1];
    const float sna = sqrtf((float)(__popcll(a0) + __popcll(a1)));
    {
        const unsigned long long j0 = packed[2 * tid], j1 = packed[2 * tid + 1];
        const float snj = sqrtf((float)(__popcll(j0) + __popcll(j1)));
        const float denom = sna * snj;
        const float dotf = (float)(__popcll(a0 & j0) + __popcll(a1 & j1));
        const float ld = 1.0f - fminf(1.0f, dotf / denom);
        const bool valid = (tid != a) && (denom > 0.f);  // 0-label -> NaN in ref -> excluded
        unsigned long long pb = __ballot(valid && (ld <= 0.2f));
        unsigned long long nb = __ballot(valid && (ld >= 0.5f));
        if (lane == 0) { pmask[w] = pb; nmask[w] = nb; }
    }
    __syncthreads();                                   // barrier 2

    if (tid == 0)
        divr[a] = (wred[0] + wred[1] + wred[2] + wred[3] + wred[4]) / (float)NB;

    // ---- triplet sum: thread t = n index t; pmask uniform per wave ----
    {
        double s = 0.0;
        const bool nbit = (nmask[w] >> lane) & 1ull;
        if (__ballot(nbit)) {                          // skip all-idle waves fast
            const float fn = fdrow[tid];
#pragma unroll
            for (int wd = 0; wd < NW; ++wd) {
                unsigned long long m = pmask[wd];      // wave-uniform trip count
                while (m) {
                    const int b = __builtin_ctzll(m);
                    m &= m - 1;
                    float v = fdrow[wd * 64 + b] - fn + 0.5f;
                    if (nbit && v > 0.f) s += (double)v;
                }
            }
        }
        for (int off = 32; off > 0; off >>= 1) s += __shfl_down(s, off);
        if (lane == 0) wsum[w] = s;
    }
    __syncthreads();                                   // barrier 3

    if (tid == 0) {
        int P = 0, N = 0;
#pragma unroll
        for (int wd = 0; wd < NW; ++wd) {
            P += __popcll(pmask[wd]);
            N += __popcll(nmask[wd]);
        }
        asum[a] = wsum[0] + wsum[1] + wsum[2] + wsum[3] + wsum[4];
        acnt[a] = P * N;
    }
}

// K2: verbatim R15 k_final.
__global__ __launch_bounds__(320) void k_final(
    const float* __restrict__ divr,
    const double* __restrict__ asum,
    const int* __restrict__ acnt,
    float* __restrict__ out)
{
    const int tid = threadIdx.x;
    __shared__ float dv[NB];
    __shared__ int alist[NANCH];
    __shared__ double sl[NANCH];
    __shared__ int cl[NANCH];

    dv[tid] = divr[tid];
    __syncthreads();

    const float ve = dv[tid];
    int rank = 0;
#pragma unroll 8
    for (int j = 0; j < NB; ++j) {
        float vj = dv[j];
        rank += (vj > ve) || (vj == ve && j < tid);
    }
    if (rank < NANCH) alist[rank] = tid;   // ranks unique; = lax.top_k order
    __syncthreads();

    if (tid < NANCH) {
        sl[tid] = asum[alist[tid]];
        cl[tid] = acnt[alist[tid]];
    }
    __syncthreads();
    if (tid == 0) {
        double S = 0.0;
        long long C = 0;
        for (int r = 0; r < NANCH; ++r) { S += sl[r]; C += cl[r]; }
        out[0] = (float)(S / ((double)C + 1e-4));
    }
}

} // namespace

extern "C" void kernel_launch(void* const* d_in, const int* in_sizes, int n_in,
                              void* d_out, int out_size, void* d_ws, size_t ws_size,
                              hipStream_t stream) {
    const int* label = (const int*)d_in[0];
    const float* src = (const float*)d_in[1];
    const float* tgt = (const float*)d_in[2];

    char* ws = (char*)d_ws;
    float* divr  = (float*)(ws + OFF_DIV);
    double* asum = (double*)(ws + OFF_ASUM);
    int* acnt    = (int*)(ws + OFF_ACNT);
    unsigned long long* packed = (unsigned long long*)(ws + OFF_PACK);
    float4* tgtT4 = (float4*)(ws + OFF_TGTT);

    k_prep <<<40, 256, 0, stream>>>(tgt, label, tgtT4, packed);
    k_main <<<NB, 320, 0, stream>>>(src, tgtT4, packed, divr, asum, acnt);
    k_final<<<1, 320, 0, stream>>>(divr, asum, acnt, (float*)d_out);
}